// Round 8
// baseline (144.172 us; speedup 1.0000x reference)
//
#include <hip/hip_runtime.h>
#include <math.h>

#define BB 2
#define LL 1024
#define CCH 512
#define HH 8
#define LN_EPSF 1e-5f

typedef short s16x8 __attribute__((ext_vector_type(8)));
typedef float fx4 __attribute__((ext_vector_type(4)));

// ---- fragment-contiguous layout ----
// All MFMA operand tensors are stored as 16(rows) x 32(k) tiles, each tile a
// contiguous 512-element block: element (r, k) at tile*512 + lane*8 + j where
// lane = ((k&31)>>3)*16 + (r&15), j = k&7. A wave's ldfrag is then ONE
// coalesced 1KB load (vs 16-way cache-line split in row-major).

__device__ __forceinline__ unsigned short f2bf(float f) {
  unsigned u = __float_as_uint(f);
  unsigned r = (u + 0x7FFFu + ((u >> 16) & 1u)) >> 16;
  return (unsigned short)r;
}
__device__ __forceinline__ float bf2f(unsigned short h) {
  return __uint_as_float(((unsigned)h) << 16);
}
__device__ __forceinline__ s16x8 ldfrag(const unsigned short* p) {
  int4 t = *(const int4*)p;
  return *(s16x8*)&t;
}
// raw v_exp_f32: computes 2^x. Logits are pre-scaled by log2(e) via the
// projection scale constants, so no per-exp v_mul is needed.
__device__ __forceinline__ float ex2(float x) {
  float r;
  asm("v_exp_f32 %0, %1" : "=v"(r) : "v"(x));
  return r;
}

// ---- DPP row_ror reductions over 16-lane rows ----
template <int CTRL>
__device__ __forceinline__ float dpp_mov(float x) {
  return __int_as_float(
      __builtin_amdgcn_update_dpp(0, __float_as_int(x), CTRL, 0xF, 0xF, true));
}
__device__ __forceinline__ float red16_sum(float v) {
  v += dpp_mov<0x121>(v);
  v += dpp_mov<0x122>(v);
  v += dpp_mov<0x124>(v);
  v += dpp_mov<0x128>(v);
  return v;
}
__device__ __forceinline__ float red16_max(float v) {
  v = fmaxf(v, dpp_mov<0x121>(v));
  v = fmaxf(v, dpp_mov<0x122>(v));
  v = fmaxf(v, dpp_mov<0x124>(v));
  v = fmaxf(v, dpp_mov<0x128>(v));
  return v;
}
__device__ __forceinline__ float wave_sum(float v) {
  v = red16_sum(v);
  v += __shfl_xor(v, 16);
  v += __shfl_xor(v, 32);
  return v;
}

// ---------------- prep ----------------
// blocks 0..2047: LayerNorm -> split bf16 xh/xl, FRAGMENT layout.
// blocks 2048..2335: weight pack -> wt_h FRAGMENT layout
//   (n-tile bases: q:0, k:32, v:64, o:96, qp:128, kp:134).
// (s=2 tiles of qt/kt are now written IN FULL by proj_mfma's qp/kp blocks --
//  no zero-tail pass, no separate aug kernel.)
__global__ __launch_bounds__(256) void prep(
    const float* __restrict__ f, const float* __restrict__ g,
    const float* __restrict__ bta, unsigned short* __restrict__ xh,
    unsigned short* __restrict__ xl, const float* __restrict__ wq,
    const float* __restrict__ wk, const float* __restrict__ wv,
    const float* __restrict__ wo, const float* __restrict__ wqp,
    const float* __restrict__ wkp, unsigned short* __restrict__ wt_h) {
  __shared__ unsigned short lh[64][68];
  __shared__ float red[8];
  const int tid = threadIdx.x;
  const int bxg = blockIdx.x;
  if (bxg < 2048) {  // ---- LayerNorm ----
    const int row = bxg;
    const int wave = tid >> 6, lane = tid & 63;
    const float* fr = f + (size_t)row * CCH;
    float2 v = *(const float2*)&fr[tid * 2];
    float s = wave_sum(v.x + v.y);
    if (lane == 0) red[wave] = s;
    __syncthreads();
    float mu = (red[0] + red[1] + red[2] + red[3]) * (1.0f / CCH);
    float dx = v.x - mu, dy = v.y - mu;
    float sq = wave_sum(dx * dx + dy * dy);
    if (lane == 0) red[4 + wave] = sq;
    __syncthreads();
    float var = (red[4] + red[5] + red[6] + red[7]) * (1.0f / CCH);
    float inv = 1.0f / sqrtf(var + LN_EPSF);
    float2 gg = *(const float2*)&g[tid * 2];
    float2 bb = *(const float2*)&bta[tid * 2];
    float ox = dx * inv * gg.x + bb.x;
    float oy = dy * inv * gg.y + bb.y;
    unsigned short h0 = f2bf(ox), h1 = f2bf(oy);
    ushort2 hv; hv.x = h0; hv.y = h1;
    ushort2 lv; lv.x = f2bf(ox - bf2f(h0)); lv.y = f2bf(oy - bf2f(h1));
    const int k0c = tid * 2;  // even
    size_t addr = ((size_t)((row >> 4) * 16 + (k0c >> 5))) * 512 +
                  (((k0c >> 3) & 3) * 16 + (row & 15)) * 8 + (k0c & 7);
    *(ushort2*)&xh[addr] = hv;
    *(ushort2*)&xl[addr] = lv;
  } else {  // ---- weight pack ----
    const int bx = bxg - 2048;
    const float* W;
    int Ncols, rowbase, kt, nt;
    if (bx < 256) {
      int mat = bx >> 6, t = bx & 63;
      kt = t >> 3; nt = t & 7; Ncols = 512;
      if (mat == 0) { W = wq; rowbase = 0; }
      else if (mat == 1) { W = wk; rowbase = 512; }
      else if (mat == 2) { W = wv; rowbase = 1024; }
      else { W = wo; rowbase = 1536; }
    } else {
      int r = bx - 256; int mat = r >> 4; int t = r & 15;
      kt = t >> 1; nt = t & 1; Ncols = 96;
      if (mat == 0) { W = wqp; rowbase = 2048; }
      else { W = wkp; rowbase = 2144; }
    }
    const int k0 = kt * 64, n0 = nt * 64;
    const int c = tid & 63;
#pragma unroll
    for (int ii = 0; ii < 16; ++ii) {
      int r = ii * 4 + (tid >> 6);  // k-local
      float val = (n0 + c < Ncols) ? W[(size_t)(k0 + r) * Ncols + n0 + c] : 0.f;
      lh[r][c] = f2bf(val);
    }
    __syncthreads();
    const int base_nt = (rowbase >> 4) + (n0 >> 4);
    const int base_kt = (k0 >> 5);
#pragma unroll
    for (int cc = 0; cc < 2; ++cc) {
      int ch = cc * 256 + tid;
      int lane2 = ch & 63, ktl = (ch >> 6) & 1, ntl = ch >> 7;
      int l16c = lane2 & 15, quadc = lane2 >> 4;
      if (n0 + ntl * 16 < Ncols) {
        unsigned short th[8] __attribute__((aligned(16)));
#pragma unroll
        for (int jj = 0; jj < 8; ++jj)
          th[jj] = lh[ktl * 32 + quadc * 8 + jj][ntl * 16 + l16c];
        *(int4*)&wt_h[((size_t)((base_nt + ntl) * 16 + base_kt + ktl)) * 512 +
                      lane2 * 8] = *(int4*)th;
      }
    }
  }
}

// ---------------- MFMA core, fragment layout ----------------
// A tiles at (mt0+i)*16 + ks; B tiles at (ntbase + min(nt0+j, ntmax))*16 + ks.
template <int MF, int NF, int TERMS>
__device__ __forceinline__ void mfma_core_frag(
    const unsigned short* __restrict__ Ah, const unsigned short* __restrict__ Al,
    const unsigned short* __restrict__ Bt, int mt0, int ntbase, int nt0,
    int ntmax, int ks0, int ks1, fx4 acc[MF][NF]) {
  const int lane = threadIdx.x & 63;
  int bt[NF];
#pragma unroll
  for (int j = 0; j < NF; ++j) {
    int nt = nt0 + j;
    if (nt > ntmax) nt = ntmax;
    bt[j] = ntbase + nt;
  }
#pragma unroll
  for (int i = 0; i < MF; ++i)
#pragma unroll
    for (int j = 0; j < NF; ++j) acc[i][j] = (fx4){0.f, 0.f, 0.f, 0.f};
  for (int ks = ks0; ks < ks1; ++ks) {
    s16x8 ah[MF], al[MF], b[NF];
#pragma unroll
    for (int i = 0; i < MF; ++i) {
      size_t off = ((size_t)((mt0 + i) * 16 + ks)) * 512 + lane * 8;
      ah[i] = ldfrag(&Ah[off]);
      if (TERMS == 2) al[i] = ldfrag(&Al[off]);
    }
#pragma unroll
    for (int j = 0; j < NF; ++j)
      b[j] = ldfrag(&Bt[((size_t)(bt[j] * 16 + ks)) * 512 + lane * 8]);
#pragma unroll
    for (int i = 0; i < MF; ++i)
#pragma unroll
      for (int j = 0; j < NF; ++j) {
        acc[i][j] = __builtin_amdgcn_mfma_f32_16x16x32_bf16(ah[i], b[j], acc[i][j], 0, 0, 0);
        if (TERMS == 2)
          acc[i][j] = __builtin_amdgcn_mfma_f32_16x16x32_bf16(al[i], b[j], acc[i][j], 0, 0, 0);
      }
  }
}

// ---------------- Fused projections, 64-row strips. grid (26, 32) ----------------
// bx 0..7: q -> qt frag-pack; 8..15: k -> kt; 16..23: v (head bx-16) -> vth
// frag layout via LDS; bx 24: qp (all 96 cols); bx 25: kp (all 96 cols).
// The qp/kp blocks also compute the per-row point-norm sums and emit the FULL
// s=2 tiles (point vals kc64..75, qs/ks aug slots kc76..79, zeros kc80..95) --
// this replaces the old separate aug_sq kernel and prep's zero-tail pass.
// qt/kt frag tiles: [bh][ltile 64][s 0..2]; vth: [bh][dtile 4][jtile 32].
// NOTE: all logit-side scales carry an extra sqrt(log2(e)) so attention logits
// land in the log2 domain (raw v_exp_f32, no per-exp multiply).
__global__ __launch_bounds__(256, 4) void proj_mfma(
    const unsigned short* __restrict__ xh, const unsigned short* __restrict__ xl,
    const unsigned short* __restrict__ wt_h,
    const float* __restrict__ bq, const float* __restrict__ bk,
    const float* __restrict__ bv, const float* __restrict__ bqp,
    const float* __restrict__ bkp, const float* __restrict__ pscale,
    unsigned short* __restrict__ qt, unsigned short* __restrict__ kt_,
    unsigned short* __restrict__ vth) {
  __shared__ unsigned short vt_lds[64][72];
  __shared__ unsigned short pt[64][104];  // qp/kp: scaled bf16 point vals
  __shared__ float hsum[64][8];           // qp/kp: 0.5*sum(v^2) per (row,head)
  const int bx = blockIdx.x;
  const int m0 = blockIdx.y * 64;
  const int tid = threadIdx.x;
  const int wave = __builtin_amdgcn_readfirstlane(tid >> 6);
  const int lane = tid & 63;
  const int quad = lane >> 4, l16 = lane & 15;
  const int mw = m0 + (wave & 1) * 32;
  const int mt0 = mw >> 4;

  if (bx < 16) {  // q or k scalar: hi-only
    const bool isq = bx < 8;
    const float* bias = isq ? bq : bk;
    unsigned short* pdst = isq ? qt : kt_;
    const int n0 = (bx & 7) * 64;
    const int nw = n0 + (wave >> 1) * 32;
    fx4 acc[2][2];
    mfma_core_frag<2, 2, 1>(xh, xh, wt_h, mt0, isq ? 0 : 32, nw >> 4, 31, 0, 16, acc);
#pragma unroll
    for (int j = 0; j < 2; ++j) {
      int n = nw + j * 16 + l16;
      int h = n >> 6, d = n & 63;
      float bb = bias[n];
#pragma unroll
      for (int i = 0; i < 2; ++i)
#pragma unroll
        for (int reg = 0; reg < 4; ++reg) {
          int row = mw + i * 16 + quad * 4 + reg;
          int bi = row >> 10, l = row & 1023;
          int bh2 = bi * 8 + h;
          // each of q,k scaled by sqrt(1/8 * log2 e) -> product 1/sqrt(64)*log2e
          float val = (acc[i][j][reg] + bb) * 0.4246609f;
          size_t tile = ((size_t)(bh2 * 64 + (l >> 4))) * 3 + (d >> 5);
          pdst[tile * 512 + (((d >> 3) & 3) * 16 + (l & 15)) * 8 + (d & 7)] = f2bf(val);
        }
    }
  } else if (bx < 24) {  // v: split-A, one head per block -> vth frag via LDS
    const int h = bx - 16;
    const int nw = h * 64 + (wave >> 1) * 32;
    fx4 acc[2][2];
    mfma_core_frag<2, 2, 2>(xh, xl, wt_h, mt0, 64, nw >> 4, 31, 0, 16, acc);
#pragma unroll
    for (int j = 0; j < 2; ++j) {
      int dl = (wave >> 1) * 32 + j * 16 + l16;  // local d 0..63
      float bb = bv[h * 64 + dl];
#pragma unroll
      for (int i = 0; i < 2; ++i)
#pragma unroll
        for (int reg = 0; reg < 4; ++reg) {
          int lm = (wave & 1) * 32 + i * 16 + quad * 4 + reg;  // local row 0..63
          vt_lds[lm][dl] = f2bf(acc[i][j][reg] + bb);
        }
    }
    __syncthreads();
    const int b = m0 >> 10, l0 = m0 & 1023;
    const int bh2 = b * 8 + h;
#pragma unroll
    for (int cc = 0; cc < 2; ++cc) {
      int ch = cc * 256 + tid;
      int lane2 = ch & 63, jt = (ch >> 6) & 1, ft = ch >> 7;
      int l16c = lane2 & 15, quadc = lane2 >> 4;
      unsigned short th[8] __attribute__((aligned(16)));
#pragma unroll
      for (int jj = 0; jj < 8; ++jj)
        th[jj] = vt_lds[jt * 32 + quadc * 8 + jj][ft * 16 + l16c];
      size_t tile = ((size_t)(bh2 * 4 + ft)) * 32 + (l0 >> 5) + jt;
      *(int4*)&vth[tile * 512 + lane2 * 8] = *(int4*)th;
    }
  } else {  // qp / kp point: all 96 cols in one block + aug sums + full s=2 tiles
    const bool isq = bx == 24;
    const float* bias = isq ? bqp : bkp;
    unsigned short* pdst = isq ? qt : kt_;
    const int nw = (wave >> 1) * 48;  // n-strip of 48 (3 tiles)
    fx4 acc[2][3];
    mfma_core_frag<2, 3, 1>(xh, xh, wt_h, mt0, isq ? 128 : 134, nw >> 4, 5, 0, 16, acc);
    // phase 1: scaled bf16 point vals -> LDS
#pragma unroll
    for (int j = 0; j < 3; ++j) {
      int n = nw + j * 16 + l16;       // [0,96)
      int h = n / 12;
      // sqrt(2 * pscale * log2 e)
      float sc = sqrtf(2.8853901f * pscale[h]);
      float bb = bias[n];
#pragma unroll
      for (int i = 0; i < 2; ++i)
#pragma unroll
        for (int reg = 0; reg < 4; ++reg) {
          int lm = (wave & 1) * 32 + i * 16 + quad * 4 + reg;  // local row 0..63
          pt[lm][n] = f2bf((acc[i][j][reg] + bb) * sc);
        }
    }
    __syncthreads();
    // phase 2: per-(row, head) sums of squares (over the bf16-rounded vals)
#pragma unroll
    for (int t2 = 0; t2 < 2; ++t2) {
      int task = tid * 2 + t2;        // [0,512)
      int row = task >> 3, h = task & 7;
      float s = 0.f;
#pragma unroll
      for (int c = 0; c < 12; ++c) {
        float x = bf2f(pt[row][h * 12 + c]);
        s += x * x;
      }
      hsum[row][h] = 0.5f * s;
    }
    __syncthreads();
    // phase 3: emit full s=2 tiles (32 tiles: 8 heads x 4 ltiles)
    const int bi = m0 >> 10, l0t = (m0 & 1023) >> 4;
#pragma unroll
    for (int it = 0; it < 8; ++it) {
      int idx = it * 256 + tid;       // [0,2048) int4 stores
      int tile = idx >> 6;            // [0,32)
      int lane2 = idx & 63;
      int h = tile >> 2, lt = tile & 3;
      int r = lane2 & 15;
      int row = lt * 16 + r;
      int kb = (lane2 >> 4) * 8;      // klocal base
      unsigned short vals[8] __attribute__((aligned(16)));
#pragma unroll
      for (int j = 0; j < 8; ++j) {
        int kl = kb + j;
        unsigned short v;
        if (kl < 12) {
          v = pt[row][h * 12 + kl];
        } else if (kl >= 16) {
          v = 0;
        } else {
          float tot = hsum[row][h];
          unsigned short hi = f2bf(tot);
          unsigned short lo = f2bf(tot - bf2f(hi));
          // q: kc76,77=-1,-1 kc78,79=qs_hi,qs_lo ; k: kc76,77=ks_hi,ks_lo kc78,79=-1,-1
          bool sumslot = isq ? (kl >= 14) : (kl < 14);
          v = sumslot ? ((kl & 1) ? lo : hi) : (unsigned short)0xBF80;
        }
        vals[j] = v;
      }
      int bh2 = bi * 8 + h;
      size_t tile_g = ((size_t)(bh2 * 64 + (l0t + lt))) * 3 + 2;
      *(int4*)&pdst[tile_g * 512 + lane2 * 8] = *(int4*)vals;
    }
  }
}

// ---------------- Flash IPA attention ----------------
// 1024 blocks: (2 batch x 8 head) x 64 Q-tiles of 16 rows; bid&7 = head keeps
// each head's K/V resident in one XCD's L2. 4 waves = 4 K-quarters (256 keys).
// 64-key softmax tiles (4 chunks of 64): one online-max update per 64 keys.
// Logits come straight out of the QK^T MFMA (aug dims carry -qs-ks, pre-scaled
// by log2 e). pb (P-transpose buffer, [16][72] shorts) is wave-private,
// ALIASED into the obuf merge region. 4-way distributed flash merge writes
// per-head O straight to global oh (frag layout) -- no atomics.
__global__ __launch_bounds__(256, 4) void ipa_attn_mfma(
    const unsigned short* __restrict__ qt, const unsigned short* __restrict__ kt_,
    const unsigned short* __restrict__ vth, unsigned short* __restrict__ oh) {
  const int bid = blockIdx.x;
  const int low3 = bid & 7;
  const int slot = bid >> 3;       // [0,128)
  const int qtile = slot & 63;     // 16-row Q tile
  const int bh = ((slot >> 6) << 3) | low3;
  const int tid = threadIdx.x;
  const int wave = tid >> 6, lane = tid & 63;
  const int quad = lane >> 4, l16 = lane & 15;
  const int kq = wave;             // K-quarter
  const int ibase = qtile * 16;

  __shared__ __align__(16) float obufF[4 * 16 * 66];  // padded [4][16][66]
  __shared__ float mred[4][16], lred[4][16];

  // wave-private pb transpose buffer aliased into this wave's obuf slice
  // (16x66 f32 = 4224 B; pb needs 16x72 shorts = 2304 B; obuf written only
  // after the last pb read; in-wave LDS ordering).
  unsigned short* pbw = (unsigned short*)&obufF[wave * 16 * 66];  // [16][72]

  s16x8 aq[3];
#pragma unroll
  for (int s = 0; s < 3; ++s)
    aq[s] = ldfrag(&qt[(((size_t)(bh * 64 + qtile)) * 3 + s) * 512 + lane * 8]);

  fx4 o[4];
#pragma unroll
  for (int f = 0; f < 4; ++f) o[f] = (fx4){0.f, 0.f, 0.f, 0.f};
  float m_r[4], l_r[4];
#pragma unroll
  for (int reg = 0; reg < 4; ++reg) { m_r[reg] = -INFINITY; l_r[reg] = 0.f; }

#pragma unroll 1
  for (int c = 0; c < 4; ++c) {
    const int j0 = kq * 256 + c * 64;
    fx4 sa[4];
#pragma unroll
    for (int f = 0; f < 4; ++f) sa[f] = (fx4){0.f, 0.f, 0.f, 0.f};
    // QK^T over 64 keys in two halves (limits live bk registers to 6 frags)
#pragma unroll
    for (int half = 0; half < 2; ++half) {
      s16x8 bk[2][3];
#pragma unroll
      for (int f = 0; f < 2; ++f)
#pragma unroll
        for (int s = 0; s < 3; ++s)
          bk[f][s] = ldfrag(
              &kt_[(((size_t)(bh * 64 + (j0 >> 4) + half * 2 + f)) * 3 + s) * 512 +
                   lane * 8]);
#pragma unroll
      for (int f = 0; f < 2; ++f)
#pragma unroll
        for (int s = 0; s < 3; ++s)
          sa[half * 2 + f] = __builtin_amdgcn_mfma_f32_16x16x32_bf16(
              aq[s], bk[f][s], sa[half * 2 + f], 0, 0, 0);
    }

    // one online-max update per 64 keys
#pragma unroll
    for (int reg = 0; reg < 4; ++reg) {
      float z0 = sa[0][reg], z1 = sa[1][reg];
      float z2 = sa[2][reg], z3 = sa[3][reg];
      float mx = red16_max(fmaxf(fmaxf(z0, z1), fmaxf(z2, z3)));
      float mnew = fmaxf(m_r[reg], mx);
      float p0 = ex2(z0 - mnew), p1 = ex2(z1 - mnew);
      float p2 = ex2(z2 - mnew), p3 = ex2(z3 - mnew);
      float alpha = ex2(m_r[reg] - mnew);
      float psum = red16_sum((p0 + p1) + (p2 + p3));
      l_r[reg] = l_r[reg] * alpha + psum;
      m_r[reg] = mnew;
      o[0][reg] *= alpha; o[1][reg] *= alpha; o[2][reg] *= alpha; o[3][reg] *= alpha;
      int rb = (quad * 4 + reg) * 72;
      pbw[rb + l16] = f2bf(p0);
      pbw[rb + 16 + l16] = f2bf(p1);
      pbw[rb + 32 + l16] = f2bf(p2);
      pbw[rb + 48 + l16] = f2bf(p3);
    }
    // V fragments loaded only now (not live across the softmax above)
    s16x8 bvh[2][4];
#pragma unroll
    for (int kt2 = 0; kt2 < 2; ++kt2)
#pragma unroll
      for (int f = 0; f < 4; ++f)
        bvh[kt2][f] = ldfrag(
            &vth[(((size_t)(bh * 4 + f)) * 32 + (j0 >> 5) + kt2) * 512 + lane * 8]);
    s16x8 ap0 = ldfrag(&pbw[l16 * 72 + quad * 8]);
    s16x8 ap1 = ldfrag(&pbw[l16 * 72 + 32 + quad * 8]);
#pragma unroll
    for (int f = 0; f < 4; ++f) {
      o[f] = __builtin_amdgcn_mfma_f32_16x16x32_bf16(ap0, bvh[0][f], o[f], 0, 0, 0);
      o[f] = __builtin_amdgcn_mfma_f32_16x16x32_bf16(ap1, bvh[1][f], o[f], 0, 0, 0);
    }
  }
  if (l16 == 0) {
#pragma unroll
    for (int reg = 0; reg < 4; ++reg) {
      mred[wave][quad * 4 + reg] = m_r[reg];
      lred[wave][quad * 4 + reg] = l_r[reg];
    }
  }
#pragma unroll
  for (int f = 0; f < 4; ++f)
#pragma unroll
    for (int reg = 0; reg < 4; ++reg)
      obufF[((size_t)(wave * 16 + quad * 4 + reg)) * 66 + f * 16 + l16] = o[f][reg];
  __syncthreads();

  // ---- distributed 4-way flash merge; write oh (frag layout) directly ----
  {
    const int b = bh >> 3, h = bh & 7;
    const int d = wave * 16 + l16;  // this wave's 16 d-columns
#pragma unroll
    for (int rr = 0; rr < 4; ++rr) {
      int row = quad * 4 + rr;
      float M = -INFINITY;
#pragma unroll
      for (int p = 0; p < 4; ++p) M = fmaxf(M, mred[p][row]);
      float L = 0.f, val = 0.f;
#pragma unroll
      for (int p = 0; p < 4; ++p) {
        float w = ex2(mred[p][row] - M);
        L += lred[p][row] * w;
        val += obufF[((size_t)(p * 16 + row)) * 66 + d] * w;
      }
      val /= L;
      int m = b * LL + ibase + row;     // token row
      int kcol = h * 64 + d;            // column in [0,512)
      size_t tile = ((size_t)(m >> 4)) * 16 + (kcol >> 5);
      oh[tile * 512 + (((kcol >> 3) & 3) * 16 + (m & 15)) * 8 + (kcol & 7)] =
          f2bf(val);
    }
  }
}

// ---------------- Output projection: plain stores, no atomics ----------------
// grid (8, 32), 256 threads. out[64 rows x 64 cols per block] =
// OH[., 512] @ Wo (wt_h n-tile base 96), K = 512 (16 k-steps).
__global__ __launch_bounds__(256, 4) void out_proj_mfma(
    const unsigned short* __restrict__ oh,
    const unsigned short* __restrict__ wt_h, const float* __restrict__ bo,
    float* __restrict__ out) {
  const int tid = threadIdx.x;
  const int wave = __builtin_amdgcn_readfirstlane(tid >> 6);
  const int lane = tid & 63;
  const int quad = lane >> 4, l16 = lane & 15;
  const int mw = blockIdx.y * 64 + (wave & 1) * 32;
  const int nw = blockIdx.x * 64 + (wave >> 1) * 32;
  fx4 acc[2][2];
  mfma_core_frag<2, 2, 1>(oh, oh, wt_h, mw >> 4, 96, nw >> 4, 31, 0, 16, acc);
#pragma unroll
  for (int j = 0; j < 2; ++j) {
    int n = nw + j * 16 + l16;
    float bb = bo[n];
#pragma unroll
    for (int i = 0; i < 2; ++i)
#pragma unroll
      for (int reg = 0; reg < 4; ++reg) {
        int row = mw + i * 16 + quad * 4 + reg;
        out[(size_t)row * 512 + n] = acc[i][j][reg] + bb;
      }
  }
}

extern "C" void kernel_launch(void* const* d_in, const int* in_sizes, int n_in,
                              void* d_out, int out_size, void* d_ws, size_t ws_size,
                              hipStream_t stream) {
  (void)in_sizes; (void)n_in; (void)out_size; (void)ws_size;
  const float* features = (const float*)d_in[0];
  const float* ln_g = (const float*)d_in[2];
  const float* ln_b = (const float*)d_in[3];
  const float* wq = (const float*)d_in[4];
  const float* bq = (const float*)d_in[5];
  const float* wk = (const float*)d_in[6];
  const float* bk = (const float*)d_in[7];
  const float* wv = (const float*)d_in[8];
  const float* bv = (const float*)d_in[9];
  const float* wqp = (const float*)d_in[10];
  const float* bqp = (const float*)d_in[11];
  const float* wkp = (const float*)d_in[12];
  const float* bkp = (const float*)d_in[13];
  const float* wo = (const float*)d_in[16];
  const float* bo = (const float*)d_in[17];
  const float* pscale = (const float*)d_in[18];
  float* out = (float*)d_out;

  char* cur = (char*)d_ws;
  const size_t NTOK = (size_t)BB * LL;  // 2048
  unsigned short* xh = (unsigned short*)cur; cur += NTOK * CCH * 2;
  unsigned short* xl = (unsigned short*)cur; cur += NTOK * CCH * 2;
  unsigned short* wt_h = (unsigned short*)cur; cur += (size_t)2240 * 512 * 2;
  unsigned short* qt = (unsigned short*)cur; cur += (size_t)16 * LL * 96 * 2;
  unsigned short* kt_ = (unsigned short*)cur; cur += (size_t)16 * LL * 96 * 2;
  unsigned short* vth = (unsigned short*)cur; cur += (size_t)16 * 64 * LL * 2;
  unsigned short* oh = (unsigned short*)cur; cur += NTOK * CCH * 2;

  prep<<<dim3(2336), 256, 0, stream>>>(features, ln_g, ln_b, xh, xl, wq, wk, wv,
                                       wo, wqp, wkp, wt_h);
  proj_mfma<<<dim3(26, 32), 256, 0, stream>>>(xh, xl, wt_h, bq, bk, bv, bqp, bkp,
                                              pscale, qt, kt_, vth);
  ipa_attn_mfma<<<dim3(1024), 256, 0, stream>>>(qt, kt_, vth, oh);
  out_proj_mfma<<<dim3(8, 32), 256, 0, stream>>>(oh, wt_h, bo, out);
}